// Round 8
// baseline (764.071 us; speedup 1.0000x reference)
//
#include <hip/hip_runtime.h>
#include <stdint.h>

#define B_    4
#define N_    2048
#define D_    4096
#define E_    64
#define TOKENS (B_ * N_)        // 8192
#define WPB   8                 // waves per block (in-block split-K)
#define TPB   16                // tokens per block
#define KCH   (D_ / WPB)        // 512 k's per wave
#define KB    2                 // k's per pipeline stage
#define NKB   (KCH / KB)        // 256 stages
#define NBLK  (TOKENS / TPB)    // 512 blocks

typedef float vfloat4 __attribute__((ext_vector_type(4)));

// ---------------------------------------------------------------------------
// K1 (fused): router GEMM (GEMV-style) + softmax/argmax/losses + d_out zero.
// Block = 512 thr = 8 waves; block owns 16 tokens; wave wv does k-chunk wv.
// lane = expert. Per k: W[k][lane] is a coalesced 256B vector load (L2);
// A[t][k] is wave-uniform, loaded via VMEM broadcast (opaque-zero VGPR in the
// address defeats s_load scalarization — round 7's failure mode). Explicit
// cur/nxt double-buffer keeps loads in flight during the fmac burst.
// No LDS in the hot loop; LDS only for the 8-way K-reduction + softmax.
// ---------------------------------------------------------------------------
__global__ __launch_bounds__(512) void k_fused(const float* __restrict__ A,
                                               const float* __restrict__ W,
                                               int* __restrict__ idx,
                                               float* __restrict__ gate,
                                               float* __restrict__ probsum,
                                               float* __restrict__ out,
                                               float* __restrict__ out_z,
                                               int qpt) {
    __shared__ float part[WPB][TPB][E_];   // 32 KB
    __shared__ float prob[TPB][E_];        // 4 KB
    __shared__ float zsq[TPB];

    const int tid  = threadIdx.x;
    const int lane = tid & 63;
    const int wv   = tid >> 6;             // 0..7
    const int tok0 = blockIdx.x * TPB;
    const int k0   = wv * KCH;

    // opaque zero (block=512 -> tid>>9 == 0, compiler can't prove):
    // forces A addresses to stay divergent -> VMEM broadcast loads.
    const int vz = (int)(threadIdx.x >> 9);

    const float* __restrict__ Wb = W + (size_t)k0 * E_ + lane;

    // A row bases for this wave's k-chunk
    const float* ab[TPB];
    #pragma unroll
    for (int t = 0; t < TPB; ++t)
        ab[t] = A + (size_t)(tok0 + t) * D_ + k0 + vz;

    float acc[TPB];
    #pragma unroll
    for (int t = 0; t < TPB; ++t) acc[t] = 0.f;

    float2 a_cur[TPB], a_nxt[TPB];
    float  w_cur[KB],  w_nxt[KB];

    #pragma unroll
    for (int t = 0; t < TPB; ++t)
        a_cur[t] = *reinterpret_cast<const float2*>(ab[t]);
    #pragma unroll
    for (int j = 0; j < KB; ++j)
        w_cur[j] = Wb[(size_t)j * E_];

    #pragma unroll 2
    for (int kb = 0; kb < NKB; ++kb) {
        const int kk = (kb + 1) * KB;
        if (kb + 1 < NKB) {                 // issue next stage's loads now
            #pragma unroll
            for (int t = 0; t < TPB; ++t)
                a_nxt[t] = *reinterpret_cast<const float2*>(ab[t] + kk);
            #pragma unroll
            for (int j = 0; j < KB; ++j)
                w_nxt[j] = Wb[(size_t)(kk + j) * E_];
        }
        #pragma unroll
        for (int t = 0; t < TPB; ++t) {
            acc[t] = fmaf(a_cur[t].x, w_cur[0], acc[t]);
            acc[t] = fmaf(a_cur[t].y, w_cur[1], acc[t]);
        }
        #pragma unroll
        for (int t = 0; t < TPB; ++t) a_cur[t] = a_nxt[t];
        #pragma unroll
        for (int j = 0; j < KB; ++j) w_cur[j] = w_nxt[j];
    }

    // ---- zero-fill slice of d_out (NT stores drain while epilogue runs)
    {
        vfloat4* zb = reinterpret_cast<vfloat4*>(out)
                    + (size_t)blockIdx.x * (size_t)qpt * 512 + tid;
        const vfloat4 z4 = {0.f, 0.f, 0.f, 0.f};
        #pragma unroll 1
        for (int s = 0; s < qpt; ++s)
            __builtin_nontemporal_store(z4, zb + (size_t)s * 512);
    }

    // ---- 8-way K reduction + per-token softmax
    #pragma unroll
    for (int t = 0; t < TPB; ++t)
        part[wv][t][lane] = acc[t];
    __syncthreads();

    #pragma unroll
    for (int j = 0; j < 2; ++j) {          // wave wv handles tokens 2wv+j
        const int t = wv * 2 + j;
        float l = 0.f;
        #pragma unroll
        for (int p = 0; p < WPB; ++p) l += part[p][t][lane];

        float m = l; int mi = lane;        // argmax, first-index tie-break
        #pragma unroll
        for (int off = 32; off > 0; off >>= 1) {
            const float om = __shfl_down(m, off);
            const int   oi = __shfl_down(mi, off);
            if (om > m || (om == m && oi < mi)) { m = om; mi = oi; }
        }
        m  = __shfl(m, 0);
        mi = __shfl(mi, 0);

        const float pe = __expf(l - m);
        float s = pe;
        #pragma unroll
        for (int off = 32; off > 0; off >>= 1) s += __shfl_down(s, off);
        s = __shfl(s, 0);

        prob[t][lane] = pe / s;
        if (lane == 0) {
            const float lse = m + logf(s);
            zsq[t]         = lse * lse;
            idx[tok0 + t]  = mi;
            gate[tok0 + t] = 1.0f / s;     // max prob
        }
    }
    __syncthreads();

    if (wv == 0) {
        float ps = 0.f;
        #pragma unroll
        for (int t = 0; t < TPB; ++t) ps += prob[t][lane];
        const int b = tok0 / N_;           // 16 | 2048: no batch crossing
        atomicAdd(&probsum[b * E_ + lane], ps);
        if (lane == 0) {
            float z = 0.f;
            #pragma unroll
            for (int t = 0; t < TPB; ++t) z += zsq[t];
            atomicAdd(out_z, z * (1.0f / (float)TOKENS));
        }
    }
}

// ---------------------------------------------------------------------------
// K2: ordered position-in-expert via wave ballot (matches reference cumsum),
// scatter into dispatch/combine + aux-loss fused. One wave per (b,e).
// ---------------------------------------------------------------------------
__global__ __launch_bounds__(64) void k_posloss(const int* __restrict__ idx,
                                                const float* __restrict__ gate,
                                                const float* __restrict__ probsum,
                                                float* __restrict__ out,
                                                float* __restrict__ out_aux,
                                                int C, size_t half) {
    const int b = blockIdx.x >> 6;
    const int e = blockIdx.x & 63;
    const int lane = threadIdx.x;
    const int*   ib = idx  + b * N_;
    const float* gb = gate + b * N_;
    float* ob = out + (size_t)b * N_ * E_ * C;   // dispatch base for batch b

    int running = 0;
    for (int step = 0; step < N_ / 64; ++step) {
        const int t = step * 64 + lane;
        const bool match = (ib[t] == e);
        const unsigned long long mask = __ballot(match);
        if (match) {
            const int p = running + __popcll(mask & ((1ull << lane) - 1ull));
            if (p < C) {
                const size_t off = (size_t)t * E_ * C + (size_t)e * C + p;
                ob[off] = 1.0f;            // dispatch
                ob[half + off] = gb[t];    // combine
            }
        }
        running += __popcll(mask);
    }
    if (lane == 0)   // aux = sum(count * probsum) * E^2/(B*E*N*N) = sum/262144
        atomicAdd(out_aux,
                  (float)running * probsum[b * E_ + e] * (1.0f / 262144.0f));
}

// ---------------------------------------------------------------------------
extern "C" void kernel_launch(void* const* d_in, const int* in_sizes, int n_in,
                              void* d_out, int out_size, void* d_ws, size_t ws_size,
                              hipStream_t stream) {
    const float* A = (const float*)d_in[0];
    const float* W = (const float*)d_in[1];
    float* out = (float*)d_out;

    const size_t half = ((size_t)out_size - 2) / 2;          // TOKENS*E*C
    const int C = (int)(half / ((size_t)TOKENS * E_));       // 40
    // float4 zero-stores per thread: (2*half/4) / (NBLK*512) = 40 for C=40
    const int qpt = (int)((half / 2) / ((size_t)NBLK * 512));

    float* gate    = (float*)d_ws;
    int*   idx     = (int*)(gate + TOKENS);
    float* probsum = (float*)(gate + 2 * TOKENS);

    float* out_aux = out + 2 * half;
    float* out_z   = out + 2 * half + 1;

    hipMemsetAsync(probsum, 0, B_ * E_ * sizeof(float), stream);
    hipMemsetAsync(out_aux, 0, 2 * sizeof(float), stream);

    k_fused<<<NBLK, 512, 0, stream>>>(A, W, idx, gate, probsum, out,
                                      out_z, qpt);
    k_posloss<<<B_ * E_, 64, 0, stream>>>(idx, gate, probsum, out, out_aux,
                                          C, half);
}